// Round 11
// baseline (325.054 us; speedup 1.0000x reference)
//
#include <hip/hip_runtime.h>

typedef unsigned short u16;
typedef float f32x4 __attribute__((ext_vector_type(4)));
typedef int   i32x4 __attribute__((ext_vector_type(4)));
typedef u16   u16x8 __attribute__((ext_vector_type(8)));

// XOR-swizzle on u16 index within a [rows]x32 bf16 tile: flips 16B-slot bits
// 3..4 with ((row>>1)&3). Measured r6/r7: SQ_LDS_BANK_CONFLICT == 0.
#define SWZ(i) ((i) ^ ((((i) >> 6) & 3) << 3))

__device__ __forceinline__ u16 f2bf(float f) {
  unsigned u = __float_as_uint(f);
  u += 0x7FFFu + ((u >> 16) & 1u);
  return (u16)(u >> 16);
}

__device__ __forceinline__ float tanh_fast(float x) {
  float e = __expf(2.0f * x);
  return 1.0f - 2.0f / (e + 1.0f);
}

__device__ __forceinline__ void mfma_bf16(f32x4& acc, i32x4 a, i32x4 b) {
  asm("v_mfma_f32_16x16x32_bf16 %0, %1, %2, %0" : "+v"(acc) : "v"(a), "v"(b));
}

// async global->LDS DMA, 16B per lane (emits global_load_lds_dwordx4).
// LDS dest is wave-uniform base + lane*16 (m104); pass per-lane base+l*16.
__device__ __forceinline__ void gload16(const u16* g, u16* l) {
  __builtin_amdgcn_global_load_lds(
      (const __attribute__((address_space(1))) void*)g,
      (__attribute__((address_space(3))) void*)l, 16, 0, 0);
}

// ------------- fused fp32 -> bf16 cast for all 4 tensors (one launch) -------
// chunk = 8 elements. text 2097152 chunks | audio 1048576 | Wt2 131072 | Wa1 131072
__global__ __launch_bounds__(256) void cast_all_kernel(
    const float* __restrict__ text, const float* __restrict__ audio,
    const float* __restrict__ w2, const float* __restrict__ w1,
    u16* __restrict__ tb, u16* __restrict__ ab,
    u16* __restrict__ w2b, u16* __restrict__ w1b) {
  const int NTOT = 3407872;
  int stride = gridDim.x * 256;
  for (int i = blockIdx.x * 256 + threadIdx.x; i < NTOT; i += stride) {
    const float* src; u16* dst; int j;
    if (i < 2097152)      { src = text;  dst = tb;  j = i; }
    else if (i < 3145728) { src = audio; dst = ab;  j = i - 2097152; }
    else if (i < 3276800) { src = w2;    dst = w2b; j = i - 3145728; }
    else                  { src = w1;    dst = w1b; j = i - 3276800; }
    const float4* s = (const float4*)src;
    float4 a = s[2 * j], b = s[2 * j + 1];
    u16x8 o;
    o[0] = f2bf(a.x); o[1] = f2bf(a.y); o[2] = f2bf(a.z); o[3] = f2bf(a.w);
    o[4] = f2bf(b.x); o[5] = f2bf(b.y); o[6] = f2bf(b.z); o[7] = f2bf(b.w);
    *(u16x8*)(dst + (size_t)8 * j) = o;
  }
}

// ---------------- fused GEMM + tanh + weighted reduce over e --------------
// sv[split][m] = sum_{n in split*256..+255} tanh( sum_k X[m,k]*W[n,k] )*wv[n]
// BM=128, BN=256 (4 N-splits), BK=32. 8 waves (2 wm x 4 wn), 64x64 per wave.
// Staging via global_load_lds DMA: LDS linear, global source pre-swizzled so
// the (r6-verified zero-conflict) SWZ read retrieves chunks unpermuted:
//   lane l of wave w loads row w*16+(l>>2), chunk (l&3)^((l>>3)&3);
//   DMA writes slot l&3  =>  LDS(r, s) holds chunk s^((r>>1)&3)  == SWZ read.
// Double-buffered, ONE barrier/K-step (implicit vmcnt(0) drain at barrier
// lands after the MFMAs -> load latency hidden; 3 blocks/CU cover the rest).
__global__ __launch_bounds__(512, 4) void score_kernel(
    const u16* __restrict__ Xa, const u16* __restrict__ Wa,
    const float* __restrict__ wva, float* __restrict__ sva,
    const u16* __restrict__ Xt, const u16* __restrict__ Wt,
    const float* __restrict__ wvt, float* __restrict__ svt) {
  __shared__ u16 At[2][4096];    // 128 x 32 bf16 per buffer (linear)
  __shared__ u16 Bt[2][8192];    // 256 x 32 bf16 per buffer (linear)

  int bx = blockIdx.x;
  const u16 *X, *W; const float* wv; float* svout; int mt, split, M;
  if (bx < 256) {
    X = Xa; W = Wa; wv = wva; svout = sva; M = 8192;
    mt = (bx >> 5) * 8 + (bx & 7); split = (bx >> 3) & 3;
  } else {
    int x = bx - 256;
    X = Xt; W = Wt; wv = wvt; svout = svt; M = 16384;
    mt = (x >> 5) * 8 + (x & 7); split = (x >> 3) & 3;
  }
  const int n0 = split * 256;

  const int t = threadIdx.x;          // 0..511
  const int wid = t >> 6, lane = t & 63;
  const int wm = wid >> 2, wn = wid & 3;
  const int lane15 = lane & 15, lg = lane >> 4;

  const u16* Xb = X + (size_t)mt * 128 * 1024;
  const u16* Wp = W + (size_t)n0 * 1024;

  // pre-swizzled per-lane global sources + linear LDS offsets
  const int srow = wid * 16 + (lane >> 2);                    // 0..127
  const int scol = (((lane & 3) ^ ((lane >> 3) & 3)) << 3);   // 0/8/16/24
  const u16* gA  = Xb + (size_t)srow * 1024 + scol;
  const u16* gB0 = Wp + (size_t)srow * 1024 + scol;
  const u16* gB1 = Wp + (size_t)(128 + srow) * 1024 + scol;
  const int lofs = wid * 512 + lane * 8;                      // u16 units

  f32x4 acc[4][4];
  #pragma unroll
  for (int mi = 0; mi < 4; ++mi)
    #pragma unroll
    for (int ni = 0; ni < 4; ++ni)
      acc[mi][ni] = (f32x4){0.f, 0.f, 0.f, 0.f};

  // ---- prologue: tile 0 -> buf 0 (barrier drains the DMA)
  gload16(gA,  At[0] + lofs);
  gload16(gB0, Bt[0] + lofs);
  gload16(gB1, Bt[0] + 4096 + lofs);
  __syncthreads();

  // ---- main loop: one barrier per K-step
  for (int kt = 0; kt < 32; ++kt) {
    const int cur = kt & 1;
    if (kt < 31) {                     // issue next-tile DMA first
      const int k1 = (kt + 1) * 32;
      gload16(gA + k1,  At[cur ^ 1] + lofs);
      gload16(gB0 + k1, Bt[cur ^ 1] + lofs);
      gload16(gB1 + k1, Bt[cur ^ 1] + 4096 + lofs);
    }
    i32x4 af[4], bfr[4];
    #pragma unroll
    for (int mi = 0; mi < 4; ++mi) {
      int rr = wm * 64 + mi * 16 + lane15;
      af[mi] = *(const i32x4*)(At[cur] + SWZ(rr * 32 + lg * 8));
    }
    #pragma unroll
    for (int ni = 0; ni < 4; ++ni) {
      int rr = wn * 64 + ni * 16 + lane15;
      bfr[ni] = *(const i32x4*)(Bt[cur] + SWZ(rr * 32 + lg * 8));
    }
    #pragma unroll
    for (int mi = 0; mi < 4; ++mi)
      #pragma unroll
      for (int ni = 0; ni < 4; ++ni)
        mfma_bf16(acc[mi][ni], af[mi], bfr[ni]);
    __syncthreads();                   // drains DMA (vmcnt) + ds_reads
  }

  // epilogue: rs[mi][r] = sum_ni tanh(C)*wv[n].
  // C/D layout (m89-verified): col = lane&15, row = (lane>>4)*4 + reg
  float wvn[4];
  #pragma unroll
  for (int ni = 0; ni < 4; ++ni) wvn[ni] = wv[n0 + wn * 64 + ni * 16 + lane15];
  float rs[4][4];
  #pragma unroll
  for (int mi = 0; mi < 4; ++mi)
    #pragma unroll
    for (int r = 0; r < 4; ++r) {
      float v = 0.f;
      #pragma unroll
      for (int ni = 0; ni < 4; ++ni)
        v += tanh_fast(acc[mi][ni][r]) * wvn[ni];
      rs[mi][r] = v;
    }

  // reduce over the 16 column-lanes; combine the 4 wn quarters via LDS
  float* sred = (float*)At;            // 512 floats, fits
  #pragma unroll
  for (int mi = 0; mi < 4; ++mi)
    #pragma unroll
    for (int r = 0; r < 4; ++r) {
      float v = rs[mi][r];
      v += __shfl_xor(v, 1);
      v += __shfl_xor(v, 2);
      v += __shfl_xor(v, 4);
      v += __shfl_xor(v, 8);
      if (lane15 == 0)
        sred[wn * 128 + wm * 64 + mi * 16 + lg * 4 + r] = v;
    }
  __syncthreads();
  if (t < 128)
    svout[(size_t)split * M + (size_t)mt * 128 + t] =
        sred[t] + sred[128 + t] + sred[256 + t] + sred[384 + t];
}

// ------ softmax over a + q-chunk + broadcast q-chunk into output rows ------
// X read as bf16 (halves read traffic; error ~3e-4 << threshold headroom).
// grid: 0..255 audio (b=bx>>4, dch=bx&15) -> out half 1; 256..511 text -> half 0.
__global__ __launch_bounds__(256) void softq_bcast_kernel(
    const u16* __restrict__ xA, const float* __restrict__ svA,
    const u16* __restrict__ xT, const float* __restrict__ svT,
    float* __restrict__ out) {
  int bx = blockIdx.x;
  int stage = bx >> 8;                  // 0 = audio branch, 1 = text branch
  int b = (bx >> 4) & 15, dch = bx & 15;
  int Acnt = stage ? 1024 : 512;
  int M = stage ? 16384 : 8192;
  const u16* x = stage ? xT : xA;
  const float* svp = stage ? svT : svA;
  int rowbase = b * Acnt;

  __shared__ float p[1024];
  __shared__ float red[256];
  __shared__ float chunk[64];
  int t = threadIdx.x;

  float mloc = -1e30f;
  for (int a = t; a < Acnt; a += 256) {
    float v = svp[rowbase + a] + svp[M + rowbase + a] +
              svp[2 * M + rowbase + a] + svp[3 * M + rowbase + a];
    p[a] = v;
    mloc = fmaxf(mloc, v);
  }
  #pragma unroll
  for (int off = 32; off; off >>= 1) mloc = fmaxf(mloc, __shfl_xor(mloc, off));
  if ((t & 63) == 0) red[t >> 6] = mloc;
  __syncthreads();
  float mx = fmaxf(fmaxf(red[0], red[1]), fmaxf(red[2], red[3]));

  float sloc = 0.f;
  for (int a = t; a < Acnt; a += 256) {
    float e = __expf(p[a] - mx);
    p[a] = e;
    sloc += e;
  }
  #pragma unroll
  for (int off = 32; off; off >>= 1) sloc += __shfl_xor(sloc, off);
  __syncthreads();
  if ((t & 63) == 0) red[t >> 6] = sloc;
  __syncthreads();
  float inv = 1.0f / (red[0] + red[1] + red[2] + red[3]);

  int dl = t & 63, ag = t >> 6;
  const u16* xb = x + (size_t)rowbase * 1024 + dch * 64 + dl;
  float acc = 0.f;
  #pragma unroll 8
  for (int a = ag; a < Acnt; a += 4)
    acc += p[a] * __uint_as_float(((unsigned)xb[(size_t)a * 1024]) << 16);
  __syncthreads();
  red[t] = acc;
  __syncthreads();
  if (t < 64) {
    float tot = red[t] + red[t + 64] + red[t + 128] + red[t + 192];
    chunk[t] = tot * inv;
  }
  __syncthreads();

  // broadcast this 64-float chunk across all L=1024 rows of the output.
  // out halves: [0] att_text (stage 1), [1] att_audio (stage 0).
  size_t base4 = ((stage ? (size_t)0 : (size_t)16777216) +
                  (size_t)b * 1048576 + (size_t)dch * 64) >> 2;
  f32x4* o4 = (f32x4*)out;
  f32x4 v = ((f32x4*)chunk)[t & 15];
  int q = t & 15;
  #pragma unroll 4
  for (int l = t >> 4; l < 1024; l += 16)
    __builtin_nontemporal_store(v, &o4[base4 + (size_t)l * 256 + q]);
}

extern "C" void kernel_launch(void* const* d_in, const int* in_sizes, int n_in,
                              void* d_out, int out_size, void* d_ws, size_t ws_size,
                              hipStream_t stream) {
  const float* text  = (const float*)d_in[0];   // (16,1024,1024)
  const float* audio = (const float*)d_in[1];   // (16, 512,1024)
  const float* Wa1   = (const float*)d_in[4];   // (1024,1024)
  const float* watt1 = (const float*)d_in[5];   // (2048,)
  const float* Wt2   = (const float*)d_in[7];   // (1024,1024)
  const float* watt2 = (const float*)d_in[10];  // (2048,)

  char* ws = (char*)d_ws;
  u16*   tb  = (u16*)(ws);                      // text bf16   33,554,432 B
  u16*   ab  = (u16*)(ws + 33554432);           // audio bf16  16,777,216 B
  u16*   w2b = (u16*)(ws + 50331648);           // Wt2 bf16     2,097,152 B
  u16*   w1b = (u16*)(ws + 52428800);           // Wa1 bf16     2,097,152 B
  float* sv2 = (float*)(ws + 54525952);         // [4][16384]     262,144 B
  float* sv1 = (float*)(ws + 54788096);         // [4][ 8192]     131,072 B

  cast_all_kernel<<<2048, 256, 0, stream>>>(text, audio, Wt2, Wa1,
                                            tb, ab, w2b, w1b);

  score_kernel<<<768, 512, 0, stream>>>(ab, w1b, watt1 + 1024, sv1,
                                        tb, w2b, watt2 + 1024, sv2);

  softq_bcast_kernel<<<512, 256, 0, stream>>>(ab, sv1, tb, sv2,
                                              (float*)d_out);
}

// Round 12
// 319.981 us; speedup vs baseline: 1.0159x; 1.0159x over previous
//
#include <hip/hip_runtime.h>

typedef unsigned short u16;
typedef float f32x4 __attribute__((ext_vector_type(4)));
typedef int   i32x4 __attribute__((ext_vector_type(4)));
typedef u16   u16x8 __attribute__((ext_vector_type(8)));

// XOR-swizzle on u16 index within a [rows]x32 bf16 tile: flips 16B-slot bits
// 3..4 with ((row>>1)&3). Measured r6/r7: SQ_LDS_BANK_CONFLICT == 0.
#define SWZ(i) ((i) ^ ((((i) >> 6) & 3) << 3))

__device__ __forceinline__ u16 f2bf(float f) {
  unsigned u = __float_as_uint(f);
  u += 0x7FFFu + ((u >> 16) & 1u);
  return (u16)(u >> 16);
}

__device__ __forceinline__ float tanh_fast(float x) {
  float e = __expf(2.0f * x);
  return 1.0f - 2.0f / (e + 1.0f);
}

__device__ __forceinline__ void mfma_bf16(f32x4& acc, i32x4 a, i32x4 b) {
  asm("v_mfma_f32_16x16x32_bf16 %0, %1, %2, %0" : "+v"(acc) : "v"(a), "v"(b));
}

// async global->LDS DMA, 16B per lane (emits global_load_lds_dwordx4).
__device__ __forceinline__ void gload16(const u16* g, u16* l) {
  __builtin_amdgcn_global_load_lds(
      (const __attribute__((address_space(1))) void*)g,
      (__attribute__((address_space(3))) void*)l, 16, 0, 0);
}

// ------------- fused fp32 -> bf16 cast for all 4 tensors (one launch) -------
__global__ __launch_bounds__(256) void cast_all_kernel(
    const float* __restrict__ text, const float* __restrict__ audio,
    const float* __restrict__ w2, const float* __restrict__ w1,
    u16* __restrict__ tb, u16* __restrict__ ab,
    u16* __restrict__ w2b, u16* __restrict__ w1b) {
  const int NTOT = 3407872;
  int stride = gridDim.x * 256;
  for (int i = blockIdx.x * 256 + threadIdx.x; i < NTOT; i += stride) {
    const float* src; u16* dst; int j;
    if (i < 2097152)      { src = text;  dst = tb;  j = i; }
    else if (i < 3145728) { src = audio; dst = ab;  j = i - 2097152; }
    else if (i < 3276800) { src = w2;    dst = w2b; j = i - 3145728; }
    else                  { src = w1;    dst = w1b; j = i - 3276800; }
    const float4* s = (const float4*)src;
    float4 a = s[2 * j], b = s[2 * j + 1];
    u16x8 o;
    o[0] = f2bf(a.x); o[1] = f2bf(a.y); o[2] = f2bf(a.z); o[3] = f2bf(a.w);
    o[4] = f2bf(b.x); o[5] = f2bf(b.y); o[6] = f2bf(b.z); o[7] = f2bf(b.w);
    *(u16x8*)(dst + (size_t)8 * j) = o;
  }
}

// ---------------- fused GEMM + tanh + weighted reduce over e --------------
// sv[split][m] = sum_{n in split*256..+255} tanh( sum_k X[m,k]*W[n,k] )*wv[n]
// BM=128, BN=256, BK=32, 8 waves (2x4), 64x64/wave. gload_lds DMA staging,
// global source pre-swizzled (r11) so the zero-conflict SWZ read works.
// NEW (T4): 3 LDS buffers, prefetch depth 2, counted s_waitcnt vmcnt(3) +
// raw s_barrier -- loads stay in flight across barriers (never drain to 0
// in the main loop). Iter kt: outstanding = tiles kt,kt+1 (6 loads);
// vmcnt(3) retires tile kt exactly. Stage of tile kt+2 (into buf[(kt-1)%3])
// is issued AFTER iter-kt's barrier => all waves' iter-(kt-1) reads of that
// buffer are done (no WAR race). Last iter waits vmcnt(0).
__global__ __launch_bounds__(512, 4) void score_kernel(
    const u16* __restrict__ Xa, const u16* __restrict__ Wa,
    const float* __restrict__ wva, float* __restrict__ sva,
    const u16* __restrict__ Xt, const u16* __restrict__ Wt,
    const float* __restrict__ wvt, float* __restrict__ svt) {
  __shared__ u16 At[3][4096];    // 128 x 32 bf16 per buffer (linear)
  __shared__ u16 Bt[3][8192];    // 256 x 32 bf16 per buffer (linear)

  int bx = blockIdx.x;
  const u16 *X, *W; const float* wv; float* svout; int mt, split, M;
  if (bx < 256) {
    X = Xa; W = Wa; wv = wva; svout = sva; M = 8192;
    mt = (bx >> 5) * 8 + (bx & 7); split = (bx >> 3) & 3;
  } else {
    int x = bx - 256;
    X = Xt; W = Wt; wv = wvt; svout = svt; M = 16384;
    mt = (x >> 5) * 8 + (x & 7); split = (x >> 3) & 3;
  }
  const int n0 = split * 256;

  const int t = threadIdx.x;          // 0..511
  const int wid = t >> 6, lane = t & 63;
  const int wm = wid >> 2, wn = wid & 3;
  const int lane15 = lane & 15, lg = lane >> 4;

  const u16* Xb = X + (size_t)mt * 128 * 1024;
  const u16* Wp = W + (size_t)n0 * 1024;

  // pre-swizzled per-lane global sources + linear LDS offsets (r11-verified)
  const int srow = wid * 16 + (lane >> 2);                    // 0..127
  const int scol = (((lane & 3) ^ ((lane >> 3) & 3)) << 3);   // 0/8/16/24
  const u16* gA  = Xb + (size_t)srow * 1024 + scol;
  const u16* gB0 = Wp + (size_t)srow * 1024 + scol;
  const u16* gB1 = Wp + (size_t)(128 + srow) * 1024 + scol;
  const int lofs = wid * 512 + lane * 8;                      // u16 units

  f32x4 acc[4][4];
  #pragma unroll
  for (int mi = 0; mi < 4; ++mi)
    #pragma unroll
    for (int ni = 0; ni < 4; ++ni)
      acc[mi][ni] = (f32x4){0.f, 0.f, 0.f, 0.f};

  // ---- prologue: tiles 0,1 -> bufs 0,1 (6 DMAs outstanding)
  gload16(gA,       At[0] + lofs);
  gload16(gB0,      Bt[0] + lofs);
  gload16(gB1,      Bt[0] + 4096 + lofs);
  gload16(gA + 32,  At[1] + lofs);
  gload16(gB0 + 32, Bt[1] + lofs);
  gload16(gB1 + 32, Bt[1] + 4096 + lofs);

  int c0 = 0, c1 = 1, c2 = 2;          // rotating buffer indices

  for (int kt = 0; kt < 32; ++kt) {
    // tile kt must be landed; keep tile kt+1's 3 loads in flight.
    if (kt != 31) asm volatile("s_waitcnt vmcnt(3)" ::: "memory");
    else          asm volatile("s_waitcnt vmcnt(0)" ::: "memory");
    __builtin_amdgcn_s_barrier();
    asm volatile("" ::: "memory");     // compiler fence: no hoist above barrier

    i32x4 af[4], bfr[4];
    #pragma unroll
    for (int mi = 0; mi < 4; ++mi) {
      int rr = wm * 64 + mi * 16 + lane15;
      af[mi] = *(const i32x4*)(At[c0] + SWZ(rr * 32 + lg * 8));
    }
    #pragma unroll
    for (int ni = 0; ni < 4; ++ni) {
      int rr = wn * 64 + ni * 16 + lane15;
      bfr[ni] = *(const i32x4*)(Bt[c0] + SWZ(rr * 32 + lg * 8));
    }
    #pragma unroll
    for (int mi = 0; mi < 4; ++mi)
      #pragma unroll
      for (int ni = 0; ni < 4; ++ni)
        mfma_bf16(acc[mi][ni], af[mi], bfr[ni]);

    if (kt < 30) {                     // stage tile kt+2 -> buf c2
      const int k2 = (kt + 2) * 32;
      gload16(gA + k2,  At[c2] + lofs);
      gload16(gB0 + k2, Bt[c2] + lofs);
      gload16(gB1 + k2, Bt[c2] + 4096 + lofs);
    }
    int tmp = c0; c0 = c1; c1 = c2; c2 = tmp;   // rotate
  }

  // epilogue: rs[mi][r] = sum_ni tanh(C)*wv[n].
  // C/D layout (m89-verified): col = lane&15, row = (lane>>4)*4 + reg
  float wvn[4];
  #pragma unroll
  for (int ni = 0; ni < 4; ++ni) wvn[ni] = wv[n0 + wn * 64 + ni * 16 + lane15];
  float rs[4][4];
  #pragma unroll
  for (int mi = 0; mi < 4; ++mi)
    #pragma unroll
    for (int r = 0; r < 4; ++r) {
      float v = 0.f;
      #pragma unroll
      for (int ni = 0; ni < 4; ++ni)
        v += tanh_fast(acc[mi][ni][r]) * wvn[ni];
      rs[mi][r] = v;
    }

  __syncthreads();                     // safe: vmcnt already 0
  // reduce over the 16 column-lanes; combine the 4 wn quarters via LDS
  float* sred = (float*)At;            // 512 floats, fits in At[0]
  #pragma unroll
  for (int mi = 0; mi < 4; ++mi)
    #pragma unroll
    for (int r = 0; r < 4; ++r) {
      float v = rs[mi][r];
      v += __shfl_xor(v, 1);
      v += __shfl_xor(v, 2);
      v += __shfl_xor(v, 4);
      v += __shfl_xor(v, 8);
      if (lane15 == 0)
        sred[wn * 128 + wm * 64 + mi * 16 + lg * 4 + r] = v;
    }
  __syncthreads();
  if (t < 128)
    svout[(size_t)split * M + (size_t)mt * 128 + t] =
        sred[t] + sred[128 + t] + sred[256 + t] + sred[384 + t];
}

// ------ softmax over a + q-chunk + broadcast q-chunk into output rows ------
__global__ __launch_bounds__(256) void softq_bcast_kernel(
    const u16* __restrict__ xA, const float* __restrict__ svA,
    const u16* __restrict__ xT, const float* __restrict__ svT,
    float* __restrict__ out) {
  int bx = blockIdx.x;
  int stage = bx >> 8;                  // 0 = audio branch, 1 = text branch
  int b = (bx >> 4) & 15, dch = bx & 15;
  int Acnt = stage ? 1024 : 512;
  int M = stage ? 16384 : 8192;
  const u16* x = stage ? xT : xA;
  const float* svp = stage ? svT : svA;
  int rowbase = b * Acnt;

  __shared__ float p[1024];
  __shared__ float red[256];
  __shared__ float chunk[64];
  int t = threadIdx.x;

  float mloc = -1e30f;
  for (int a = t; a < Acnt; a += 256) {
    float v = svp[rowbase + a] + svp[M + rowbase + a] +
              svp[2 * M + rowbase + a] + svp[3 * M + rowbase + a];
    p[a] = v;
    mloc = fmaxf(mloc, v);
  }
  #pragma unroll
  for (int off = 32; off; off >>= 1) mloc = fmaxf(mloc, __shfl_xor(mloc, off));
  if ((t & 63) == 0) red[t >> 6] = mloc;
  __syncthreads();
  float mx = fmaxf(fmaxf(red[0], red[1]), fmaxf(red[2], red[3]));

  float sloc = 0.f;
  for (int a = t; a < Acnt; a += 256) {
    float e = __expf(p[a] - mx);
    p[a] = e;
    sloc += e;
  }
  #pragma unroll
  for (int off = 32; off; off >>= 1) sloc += __shfl_xor(sloc, off);
  __syncthreads();
  if ((t & 63) == 0) red[t >> 6] = sloc;
  __syncthreads();
  float inv = 1.0f / (red[0] + red[1] + red[2] + red[3]);

  int dl = t & 63, ag = t >> 6;
  const u16* xb = x + (size_t)rowbase * 1024 + dch * 64 + dl;
  float acc = 0.f;
  #pragma unroll 8
  for (int a = ag; a < Acnt; a += 4)
    acc += p[a] * __uint_as_float(((unsigned)xb[(size_t)a * 1024]) << 16);
  __syncthreads();
  red[t] = acc;
  __syncthreads();
  if (t < 64) {
    float tot = red[t] + red[t + 64] + red[t + 128] + red[t + 192];
    chunk[t] = tot * inv;
  }
  __syncthreads();

  size_t base4 = ((stage ? (size_t)0 : (size_t)16777216) +
                  (size_t)b * 1048576 + (size_t)dch * 64) >> 2;
  f32x4* o4 = (f32x4*)out;
  f32x4 v = ((f32x4*)chunk)[t & 15];
  int q = t & 15;
  #pragma unroll 4
  for (int l = t >> 4; l < 1024; l += 16)
    __builtin_nontemporal_store(v, &o4[base4 + (size_t)l * 256 + q]);
}

extern "C" void kernel_launch(void* const* d_in, const int* in_sizes, int n_in,
                              void* d_out, int out_size, void* d_ws, size_t ws_size,
                              hipStream_t stream) {
  const float* text  = (const float*)d_in[0];   // (16,1024,1024)
  const float* audio = (const float*)d_in[1];   // (16, 512,1024)
  const float* Wa1   = (const float*)d_in[4];   // (1024,1024)
  const float* watt1 = (const float*)d_in[5];   // (2048,)
  const float* Wt2   = (const float*)d_in[7];   // (1024,1024)
  const float* watt2 = (const float*)d_in[10];  // (2048,)

  char* ws = (char*)d_ws;
  u16*   tb  = (u16*)(ws);                      // text bf16   33,554,432 B
  u16*   ab  = (u16*)(ws + 33554432);           // audio bf16  16,777,216 B
  u16*   w2b = (u16*)(ws + 50331648);           // Wt2 bf16     2,097,152 B
  u16*   w1b = (u16*)(ws + 52428800);           // Wa1 bf16     2,097,152 B
  float* sv2 = (float*)(ws + 54525952);         // [4][16384]     262,144 B
  float* sv1 = (float*)(ws + 54788096);         // [4][ 8192]     131,072 B

  cast_all_kernel<<<2048, 256, 0, stream>>>(text, audio, Wt2, Wa1,
                                            tb, ab, w2b, w1b);

  score_kernel<<<768, 512, 0, stream>>>(ab, w1b, watt1 + 1024, sv1,
                                        tb, w2b, watt2 + 1024, sv2);

  softq_bcast_kernel<<<512, 256, 0, stream>>>(ab, sv1, tb, sv2,
                                              (float*)d_out);
}